// Round 11
// baseline (275.916 us; speedup 1.0000x reference)
//
#include <hip/hip_runtime.h>
#include <stdint.h>
#include <stddef.h>

// ---------------------------------------------------------------------------
// BSplineKANLayer — R13: BN=512 fused kernel (gen-once), 8 waves, G=2.
// R12 post-mortem: fused 141us; across R10<->R12 the ABSOLUTE busy times are
// constant (MFMA ~33us, VALU ~58us) -> kernel is VALU-work-bound; scheduling
// is not the lever, total gen work is. With BN=256, each basis value was
// computed by 2 blocks (2 n-halves). R13 tiles BM=64 x BN=512 (full N):
// every basis eval happens ONCE globally -> gen VALU halves.
//   - 256 blocks (1/CU), 512 thr (8 waves = 2/SIMD, same as R12's 2x4).
//   - G=2 k-grouping: [stage 2 B-tiles (8 gloads/wave) + 1 eval/thread]
//     -> bar -> 2x[ds_read + 16 MFMA] -> bar.  LDS 72KB.
//   - basis8 rewritten without pointer-cast scatter (rule-#20 hygiene).
//   - prepb+consts merged into one launch.
// Layouts/rotation identical to R10-R12 (all passed, absmax 0.0105).
// ---------------------------------------------------------------------------

typedef __attribute__((ext_vector_type(8))) _Float16 half8;  // 8 fp16 = 4 VGPRs
typedef __attribute__((ext_vector_type(4))) float f32x4;

#define IN_DIM   512
#define OUT_DIM  512
#define BATCH    16384
#define KCH      576     // uint4 chunks per row: 4608 fp16 = 576 * 16B

// RNE f32 -> fp16 pair packed in a uint (a low 16, b high 16)
__device__ __forceinline__ unsigned pk2(float a, float b) {
  _Float16 ha = (_Float16)a, hb = (_Float16)b;   // v_cvt_f16_f32 (RNE)
  unsigned short ua = __builtin_bit_cast(unsigned short, ha);
  unsigned short ub = __builtin_bit_cast(unsigned short, hb);
  return (unsigned)ua | ((unsigned)ub << 16);
}
__device__ __forceinline__ uint4 pk8(float4 a, float4 b) {
  uint4 r;
  r.x = pk2(a.x, a.y); r.y = pk2(a.z, a.w);
  r.z = pk2(b.x, b.y); r.w = pk2(b.z, b.w);
  return r;
}
__device__ __forceinline__ float4 silu4(float4 v) {
  float4 r;
  r.x = v.x / (1.f + __expf(-v.x));
  r.y = v.y / (1.f + __expf(-v.y));
  r.z = v.z / (1.f + __expf(-v.z));
  r.w = v.w / (1.f + __expf(-v.w));
  return r;
}

// branchless 64->32 funnel extract: bits [amt, amt+32) of p, 0 outside [.]
__device__ __forceinline__ uint32_t fsh(uint64_t p, int amt) {
  uint32_t lo = (uint32_t)(p >> (amt & 63));
  lo = (amt >= 0 && amt < 64) ? lo : 0u;
  uint32_t hi = (uint32_t)(p << ((-amt) & 63));
  hi = (amt < 0 && amt > -64) ? hi : 0u;
  return lo | hi;
}

// Windowed cubic basis (uniform grid; matches reference's single-step-denom
// recursion exactly — verified R5..R12): 8 fp16 values for one (row,dim).
// Rewritten: direct field assignment, no pointer-cast scatter loop.
__device__ __forceinline__ uint4 basis8(float xv, float g0, float rh) {
  float u  = (xv - g0) * rh;
  float tf = floorf(u);
  float f  = u - tf;
  int   t  = (int)tf;
  bool valid = (u >= 0.f) && (u < 11.f);
  t = min(max(t, 0), 10);
  float f2 = f * f, f3 = f2 * f;
  float omf = 1.f - f;
  float v0 = omf * omf * omf;                          // j = t-3
  float v1 = fmaf(f2, fmaf(3.f, f, -6.f), 4.f);        // j = t-2
  float v2 = fmaf(f, fmaf(f, fmaf(-3.f, f, 3.f), 3.f), 1.f);  // j = t-1
  float v3 = f3;                                       // j = t
  uint64_t pack = ((uint64_t)pk2(v2, v3) << 32) | (uint64_t)pk2(v0, v1);
  pack = valid ? pack : 0ull;
  const int base = 48 - 16 * t;                        // in [-112, 48]
  uint4 r;
  r.x = fsh(pack, base);
  r.y = fsh(pack, base + 32);
  r.z = fsh(pack, base + 64);
  r.w = fsh(pack, base + 96);
  return r;
}

// ===========================================================================
// Kernel 1: merged prep — blocks 0..1151 pack B16 (4.7 MB), blocks 1152..1153
// compute per-dim consts (g0, 1/softplus). One launch.
// B16 stored slot s = kt*4 + sc of row n holds logical chunk c = (sc-rot)&3,
// rot = (n>>1)&3:  kt<128: dim = 128c+kt -> coeffs; kt>=128: j=4(kt-128)+c
// -> bwt.
// ===========================================================================
__global__ __launch_bounds__(256) void kan_prep0(
    const float* __restrict__ coeffs,  // (512,4096)
    const float* __restrict__ bwt,     // (512,512)
    const float* __restrict__ gsl,     // (512,11)
    const float* __restrict__ gstart,  // (512,1)
    uint4* __restrict__ B16,           // [512][576]
    float2* __restrict__ cst)          // (512,)
{
  const int bid = blockIdx.x;
  if (bid < 1152) {
    int id = bid * 256 + threadIdx.x;                  // < 512*576
    int n  = id / KCH;
    int s  = id - n * KCH;
    int kt = s >> 2, sc = s & 3;
    int rot = (n >> 1) & 3;
    int c   = (sc - rot) & 3;
    const float* src;
    if (kt < 128) {
      int dim = 128 * c + kt;
      src = coeffs + (size_t)n * 4096 + dim * 8;
    } else {
      int j = 4 * (kt - 128) + c;
      src = bwt + (size_t)n * 512 + j * 8;
    }
    float4 a = *(const float4*)src, b = *(const float4*)(src + 4);
    B16[id] = pk8(a, b);
  } else {
    int d = (bid - 1152) * 256 + threadIdx.x;
    if (d < IN_DIM) {
      float v  = gsl[d * 11];                          // all 11 identical
      float sp = fmaxf(v, 0.f) + log1pf(expf(-fabsf(v)));  // softplus = h
      cst[d] = make_float2(gstart[d], 1.f / sp);
    }
  }
}

// ===========================================================================
// Kernel 2: fused basis-gen + GEMM + epilogue. BM=64 x BN=512, G=2.
// grid = 256 (XCD-chunked: XCD x gets m-panels [x*32,(x+1)*32)), 512 thr.
// LDS: Bs[2][2048] (64KB) + As[2][256] (8KB) = 72KB -> 1 block/CU, 8 waves.
// Per group g (tiles 2g, 2g+1):
//   stage 16 gloads (8/wave... 4 per tile per wave) + 1 basis eval/thread
//   -> bar -> 2 x [8 ds_read_b128 + 16 MFMA] per wave -> bar.
// ===========================================================================
__device__ __forceinline__ void gload_lds16(const uint4* g, uint4* l) {
  __builtin_amdgcn_global_load_lds(
      (const __attribute__((address_space(1))) void*)g,
      (__attribute__((address_space(3))) void*)l, 16, 0, 0);
}

__global__ __launch_bounds__(512, 2) void kan_fused(
    const float* __restrict__ x,       // (16384,512)
    const uint4* __restrict__ B16,     // [512][576] packed fp16
    const float2* __restrict__ cst,    // (512,) per-dim (g0, 1/h)
    const float* __restrict__ rsc,     // (1,)
    float* __restrict__ out)           // (16384,512)
{
  __shared__ uint4 Bs[2][2048];        // [par][512 n-rows][4 chunks] = 64 KB
  __shared__ uint4 As[2][256];         // [par][64 rows][4 chunks]    =  8 KB

  const int tid  = threadIdx.x;        // 0..511
  const int lane = tid & 63;
  const int wv   = tid >> 6;           // 0..7

  // XCD-chunked bijective swizzle (256 = 8 * 32).
  const int bid  = blockIdx.x;
  const int wg   = ((bid & 7) << 5) | (bid >> 3);
  const int row0 = wg << 6;            // m-panel * 64

  const int q    = lane >> 4;          // k-chunk 0..3
  const int l15  = lane & 15;
  const int cq   = (q + ((l15 >> 1) & 3)) & 3;   // read-side un-rotation

  // gen mapping: thread = (grow, ggc, gpar) = (tid>>3, (tid>>1)&3, tid&1).
  // Per group it evals dim for tile kt = 2g + gpar, chunk ggc, local row grow.
  const int grow  = tid >> 3;          // 0..63
  const int ggc   = (tid >> 1) & 3;    // logical chunk
  const int gpar  = tid & 1;           // tile parity within group
  const int aslot = grow * 4 + ((ggc + (grow >> 1)) & 3);  // rotated As slot
  const float* xrow = x + (size_t)(row0 + grow) * IN_DIM;

  // B staging: wave wv fills Bs[par] slots [wv*256 + h*64, +64), h=0..3.
  // Global src for slot s at tile kt: B16[(s>>2)*576 + kt*4 + (s&3)].
  const uint4* gsb[4];
  #pragma unroll
  for (int h = 0; h < 4; ++h) {
    int s = wv * 256 + h * 64 + lane;
    gsb[h] = B16 + (size_t)(s >> 2) * KCH + (s & 3);
  }

  f32x4 acc[4][4];
  #pragma unroll
  for (int a = 0; a < 4; ++a)
    #pragma unroll
    for (int b = 0; b < 4; ++b)
      acc[a][b] = (f32x4){0.f, 0.f, 0.f, 0.f};

  // ==== 72 groups of 2 k-tiles: 64 spline + 8 silu ====
  for (int g = 0; g < 72; ++g) {
    // ---- stage both tiles' B (8 gloads per wave) ----
    #pragma unroll
    for (int par = 0; par < 2; ++par) {
      const int kt = 2 * g + par;
      #pragma unroll
      for (int h = 0; h < 4; ++h)
        gload_lds16(gsb[h] + kt * 4, &Bs[par][wv * 256 + h * 64]);
    }
    // ---- gen: exactly one eval per thread (gen-once globally) ----
    {
      const int kt = 2 * g + gpar;
      uint4 av;
      if (kt < 128) {
        const int dim = 128 * ggc + kt;
        float2 c = cst[dim];
        av = basis8(xrow[dim], c.x, c.y);
      } else {
        const int j = 4 * (kt - 128) + ggc;
        const float* xs = xrow + j * 8;
        float4 a_ = *(const float4*)xs, b_ = *(const float4*)(xs + 4);
        av = pk8(silu4(a_), silu4(b_));
      }
      As[gpar][aslot] = av;
    }
    __syncthreads();                                   // drains vm + lgkm

    // ---- compute 2 tiles: 32 MFMA per wave ----
    #pragma unroll
    for (int par = 0; par < 2; ++par) {
      half8 af[4], bg[4];
      #pragma unroll
      for (int tm = 0; tm < 4; ++tm)
        af[tm] = *(const half8*)&As[par][(tm * 16 + l15) * 4 + cq];
      #pragma unroll
      for (int tn = 0; tn < 4; ++tn)
        bg[tn] = *(const half8*)&Bs[par][(wv * 64 + tn * 16 + l15) * 4 + cq];
      #pragma unroll
      for (int tm = 0; tm < 4; ++tm)
        #pragma unroll
        for (int tn = 0; tn < 4; ++tn)
          acc[tm][tn] = __builtin_amdgcn_mfma_f32_16x16x32_f16(
              af[tm], bg[tn], acc[tm][tn], 0, 0, 0);
    }
    __syncthreads();                                   // protect As/Bs reuse
  }

  // ===== epilogue: + res_scale*x, tanh, store. C/D row=(lane>>4)*4+reg ====
  const float rs = rsc[0];
  #pragma unroll
  for (int tm = 0; tm < 4; ++tm) {
    #pragma unroll
    for (int tn = 0; tn < 4; ++tn) {
      #pragma unroll
      for (int r = 0; r < 4; ++r) {
        int m = row0 + tm * 16 + q * 4 + r;
        int n = wv * 64 + tn * 16 + l15;
        float xg = x[(size_t)m * IN_DIM + n];
        float y  = acc[tm][tn][r] + rs * xg;
        float e  = __expf(-2.f * fabsf(y));
        float t  = copysignf((1.f - e) / (1.f + e), y);
        out[(size_t)m * OUT_DIM + n] = t;
      }
    }
  }
}

// ===========================================================================
// Fallback: verified R5 fused kernel (used only if workspace is too small).
// ===========================================================================
__device__ __forceinline__ int swz(int r, int c) {
  return r * 4 + ((c + (r >> 1)) & 3);
}

__global__ __launch_bounds__(256, 2) void kan_main(
    const float* __restrict__ x, const float* __restrict__ coeffs,
    const float* __restrict__ bwt, const float* __restrict__ gsl,
    const float* __restrict__ gstart, const float* __restrict__ rsc,
    float* __restrict__ out)
{
  __shared__ uint4 At[512];
  __shared__ uint4 Bt[512];
  __shared__ float2 Cs[512];

  const int tid  = threadIdx.x;
  const int lane = tid & 63;
  const int wv   = tid >> 6;
  const int row0 = blockIdx.y << 7;
  const int n0   = blockIdx.x << 7;

  const int q    = lane >> 4;
  const int l15  = lane & 15;
  const int wrow = (wv >> 1) << 6;
  const int wcol = (wv & 1) << 6;

  for (int d = tid; d < IN_DIM; d += 256) {
    float v  = gsl[d * 11];
    float sp = fmaxf(v, 0.f) + log1pf(expf(-fabsf(v)));
    Cs[d] = make_float2(gstart[d], 1.f / sp);
  }
  __syncthreads();

  f32x4 acc[4][4];
  #pragma unroll
  for (int a = 0; a < 4; ++a)
    #pragma unroll
    for (int b = 0; b < 4; ++b)
      acc[a][b] = (f32x4){0.f, 0.f, 0.f, 0.f};

  const int br0 = tid >> 2,        bc0 = tid & 3;
  const int br1 = (tid + 256) >> 2, bc1 = tid & 3;

  auto do_mfma = [&]() {
    half8 af[4], bg[4];
    #pragma unroll
    for (int tm = 0; tm < 4; ++tm) {
      int m = wrow + tm * 16 + l15;
      af[tm] = *(const half8*)&At[swz(m, q)];
    }
    #pragma unroll
    for (int tn = 0; tn < 4; ++tn) {
      int n = wcol + tn * 16 + l15;
      bg[tn] = *(const half8*)&Bt[swz(n, q)];
    }
    #pragma unroll
    for (int tm = 0; tm < 4; ++tm)
      #pragma unroll
      for (int tn = 0; tn < 4; ++tn)
        acc[tm][tn] = __builtin_amdgcn_mfma_f32_16x16x32_f16(
            af[tm], bg[tn], acc[tm][tn], 0, 0, 0);
  };

  const float* bp0 = coeffs + (size_t)(n0 + br0) * 4096 + 1024 * bc0;
  const float* bp1 = coeffs + (size_t)(n0 + br1) * 4096 + 1024 * bc1;
  const float* xp0 = x + (size_t)(row0 + lane) * IN_DIM + 128 * wv;
  const float* xp1 = xp0 + (size_t)64 * IN_DIM;

  for (int kt4 = 0; kt4 < 32; ++kt4) {
    float4 xa = *(const float4*)(xp0 + kt4 * 4);
    float4 xb = *(const float4*)(xp1 + kt4 * 4);
    float xr0[4] = {xa.x, xa.y, xa.z, xa.w};
    float xr1[4] = {xb.x, xb.y, xb.z, xb.w};
    #pragma unroll
    for (int j = 0; j < 4; ++j) {
      const int kt = kt4 * 4 + j;
      const float* s0 = bp0 + kt * 8;
      const float* s1 = bp1 + kt * 8;
      float4 b0a = *(const float4*)(s0), b0b = *(const float4*)(s0 + 4);
      float4 b1a = *(const float4*)(s1), b1b = *(const float4*)(s1 + 4);

      float2 c = Cs[128 * wv + kt];
      uint4 p0 = basis8(xr0[j], c.x, c.y);
      uint4 p1 = basis8(xr1[j], c.x, c.y);

      Bt[swz(br0, bc0)] = pk8(b0a, b0b);
      Bt[swz(br1, bc1)] = pk8(b1a, b1b);
      At[swz(lane, wv)]      = p0;
      At[swz(lane + 64, wv)] = p1;
      __syncthreads();
      do_mfma();
      __syncthreads();
    }
  }

  for (int kt = 0; kt < 16; ++kt) {
    const int k0 = kt * 32;
    const float* s0 = bwt + (size_t)(n0 + br0) * 512 + k0 + bc0 * 8;
    const float* s1 = bwt + (size_t)(n0 + br1) * 512 + k0 + bc1 * 8;
    float4 b0a = *(const float4*)(s0), b0b = *(const float4*)(s0 + 4);
    float4 b1a = *(const float4*)(s1), b1b = *(const float4*)(s1 + 4);

    uint4 p[2];
    #pragma unroll
    for (int rr = 0; rr < 2; ++rr) {
      int idx = tid + rr * 256;
      int r = idx >> 2, cch = idx & 3;
      const float* xs = x + (size_t)(row0 + r) * IN_DIM + k0 + cch * 8;
      float4 xc = *(const float4*)(xs), xd = *(const float4*)(xs + 4);
      float f[8] = {xc.x, xc.y, xc.z, xc.w, xd.x, xd.y, xd.z, xd.w};
      #pragma unroll
      for (int jj = 0; jj < 8; ++jj) f[jj] = f[jj] / (1.f + __expf(-f[jj]));
      p[rr].x = pk2(f[0], f[1]); p[rr].y = pk2(f[2], f[3]);
      p[rr].z = pk2(f[4], f[5]); p[rr].w = pk2(f[6], f[7]);
    }

    Bt[swz(br0, bc0)] = pk8(b0a, b0b);
    Bt[swz(br1, bc1)] = pk8(b1a, b1b);
    #pragma unroll
    for (int rr = 0; rr < 2; ++rr) {
      int idx = tid + rr * 256;
      At[swz(idx >> 2, idx & 3)] = p[rr];
    }
    __syncthreads();
    do_mfma();
    __syncthreads();
  }

  const float rs = rsc[0];
  #pragma unroll
  for (int tm = 0; tm < 4; ++tm) {
    #pragma unroll
    for (int tn = 0; tn < 4; ++tn) {
      #pragma unroll
      for (int r = 0; r < 4; ++r) {
        int m = row0 + wrow + tm * 16 + q * 4 + r;
        int n = n0 + wcol + tn * 16 + l15;
        float xv = x[(size_t)m * IN_DIM + n];
        float y  = acc[tm][tn][r] + rs * xv;
        float e  = __expf(-2.f * fabsf(y));
        float t  = copysignf((1.f - e) / (1.f + e), y);
        out[(size_t)m * OUT_DIM + n] = t;
      }
    }
  }
}

// ---------------------------------------------------------------------------
extern "C" void kernel_launch(void* const* d_in, const int* in_sizes, int n_in,
                              void* d_out, int out_size, void* d_ws, size_t ws_size,
                              hipStream_t stream) {
  const float* x      = (const float*)d_in[0];
  const float* coeffs = (const float*)d_in[1];
  const float* bwt    = (const float*)d_in[2];
  const float* gsl    = (const float*)d_in[3];
  const float* gstart = (const float*)d_in[4];
  const float* rsc    = (const float*)d_in[5];
  float* out = (float*)d_out;
  (void)in_sizes; (void)n_in; (void)out_size;

  const size_t needB = (size_t)OUT_DIM * KCH * 16;   // 4,718,592 B
  const size_t needC = (size_t)IN_DIM * 8;           //     4,096 B

  if (d_ws != nullptr && ws_size >= needB + needC) {
    uint4*  B16 = (uint4*)d_ws;
    float2* cst = (float2*)((char*)d_ws + needB);
    hipLaunchKernelGGL(kan_prep0, dim3(1154), dim3(256), 0, stream,
                       coeffs, bwt, gsl, gstart, B16, cst);
    hipLaunchKernelGGL(kan_fused, dim3(256), dim3(512), 0, stream,
                       x, (const uint4*)B16, (const float2*)cst, rsc, out);
  } else {
    hipLaunchKernelGGL(kan_main, dim3(4, 128), dim3(256), 0, stream,
                       x, coeffs, bwt, gsl, gstart, rsc, out);
  }
}

// Round 13
// 253.349 us; speedup vs baseline: 1.0891x; 1.0891x over previous
//
#include <hip/hip_runtime.h>
#include <stdint.h>
#include <stddef.h>

// ---------------------------------------------------------------------------
// BSplineKANLayer — R14 (resubmitted unchanged after R12-round infra timeout).
// R13 post-mortem: gen-once halved VALU busy (58->36us, as predicted) but
// fused went 141->216us: gen issued a per-thread SCALAR x load immediately
// before basis8 used it -> ~300-900cyc exposed VMEM latency per group; plus
// G=2 doubled barrier count at 1 block/CU (no co-resident block to overlap).
// R14 keeps BM=64 x BN=512 gen-once and fixes both:
//   - gen inputs (x, cst) prefetched ONE GROUP AHEAD into registers, issued
//     right after staging -> use is ~600cyc later, latency hidden.
//   - G=4: [stage 16 gloads/wave + prefetch + gen 2 evals from regs] -> bar
//     -> 4x[ds_read + 16 MFMA/wave] -> bar. 36 groups, 72 barriers.
//   - LDS 144KB (Bs[4] 128K + As[4] 16K), 1 block/CU, 8 waves.
// Layouts/rotation identical to R10-R13 (all passed, absmax 0.0105).
// ---------------------------------------------------------------------------

typedef __attribute__((ext_vector_type(8))) _Float16 half8;  // 8 fp16 = 4 VGPRs
typedef __attribute__((ext_vector_type(4))) float f32x4;

#define IN_DIM   512
#define OUT_DIM  512
#define BATCH    16384
#define KCH      576     // uint4 chunks per row: 4608 fp16 = 576 * 16B

// RNE f32 -> fp16 pair packed in a uint (a low 16, b high 16)
__device__ __forceinline__ unsigned pk2(float a, float b) {
  _Float16 ha = (_Float16)a, hb = (_Float16)b;   // v_cvt_f16_f32 (RNE)
  unsigned short ua = __builtin_bit_cast(unsigned short, ha);
  unsigned short ub = __builtin_bit_cast(unsigned short, hb);
  return (unsigned)ua | ((unsigned)ub << 16);
}
__device__ __forceinline__ uint4 pk8(float4 a, float4 b) {
  uint4 r;
  r.x = pk2(a.x, a.y); r.y = pk2(a.z, a.w);
  r.z = pk2(b.x, b.y); r.w = pk2(b.z, b.w);
  return r;
}
__device__ __forceinline__ float4 silu4(float4 v) {
  float4 r;
  r.x = v.x / (1.f + __expf(-v.x));
  r.y = v.y / (1.f + __expf(-v.y));
  r.z = v.z / (1.f + __expf(-v.z));
  r.w = v.w / (1.f + __expf(-v.w));
  return r;
}

// branchless 64->32 funnel extract: bits [amt, amt+32) of p, 0 outside range
__device__ __forceinline__ uint32_t fsh(uint64_t p, int amt) {
  uint32_t lo = (uint32_t)(p >> (amt & 63));
  lo = (amt >= 0 && amt < 64) ? lo : 0u;
  uint32_t hi = (uint32_t)(p << ((-amt) & 63));
  hi = (amt < 0 && amt > -64) ? hi : 0u;
  return lo | hi;
}

// Windowed cubic basis (uniform grid; matches reference's single-step-denom
// recursion exactly — verified R5..R13): 8 fp16 values for one (row,dim).
__device__ __forceinline__ uint4 basis8(float xv, float g0, float rh) {
  float u  = (xv - g0) * rh;
  float tf = floorf(u);
  float f  = u - tf;
  int   t  = (int)tf;
  bool valid = (u >= 0.f) && (u < 11.f);
  t = min(max(t, 0), 10);
  float f2 = f * f, f3 = f2 * f;
  float omf = 1.f - f;
  float v0 = omf * omf * omf;                          // j = t-3
  float v1 = fmaf(f2, fmaf(3.f, f, -6.f), 4.f);        // j = t-2
  float v2 = fmaf(f, fmaf(f, fmaf(-3.f, f, 3.f), 3.f), 1.f);  // j = t-1
  float v3 = f3;                                       // j = t
  uint64_t pack = ((uint64_t)pk2(v2, v3) << 32) | (uint64_t)pk2(v0, v1);
  pack = valid ? pack : 0ull;
  const int base = 48 - 16 * t;                        // in [-112, 48]
  uint4 r;
  r.x = fsh(pack, base);
  r.y = fsh(pack, base + 32);
  r.z = fsh(pack, base + 64);
  r.w = fsh(pack, base + 96);
  return r;
}

// ===========================================================================
// Kernel 1: merged prep — blocks 0..1151 pack B16 (4.7 MB), blocks 1152..1153
// compute per-dim consts (g0, 1/softplus). One launch.
// B16 stored slot s = kt*4 + sc of row n holds logical chunk c = (sc-rot)&3,
// rot = (n>>1)&3:  kt<128: dim = 128c+kt -> coeffs; kt>=128: j=4(kt-128)+c
// -> bwt.
// ===========================================================================
__global__ __launch_bounds__(256) void kan_prep0(
    const float* __restrict__ coeffs,  // (512,4096)
    const float* __restrict__ bwt,     // (512,512)
    const float* __restrict__ gsl,     // (512,11)
    const float* __restrict__ gstart,  // (512,1)
    uint4* __restrict__ B16,           // [512][576]
    float2* __restrict__ cst)          // (512,)
{
  const int bid = blockIdx.x;
  if (bid < 1152) {
    int id = bid * 256 + threadIdx.x;                  // < 512*576
    int n  = id / KCH;
    int s  = id - n * KCH;
    int kt = s >> 2, sc = s & 3;
    int rot = (n >> 1) & 3;
    int c   = (sc - rot) & 3;
    const float* src;
    if (kt < 128) {
      int dim = 128 * c + kt;
      src = coeffs + (size_t)n * 4096 + dim * 8;
    } else {
      int j = 4 * (kt - 128) + c;
      src = bwt + (size_t)n * 512 + j * 8;
    }
    float4 a = *(const float4*)src, b = *(const float4*)(src + 4);
    B16[id] = pk8(a, b);
  } else {
    int d = (bid - 1152) * 256 + threadIdx.x;
    if (d < IN_DIM) {
      float v  = gsl[d * 11];                          // all 11 identical
      float sp = fmaxf(v, 0.f) + log1pf(expf(-fabsf(v)));  // softplus = h
      cst[d] = make_float2(gstart[d], 1.f / sp);
    }
  }
}

// ===========================================================================
// Kernel 2: fused basis-gen + GEMM + epilogue. BM=64 x BN=512, G=4.
// grid = 256 (XCD-chunked), 512 thr (8 waves). LDS 144KB, 1 block/CU.
// ===========================================================================
__device__ __forceinline__ void gload_lds16(const uint4* g, uint4* l) {
  __builtin_amdgcn_global_load_lds(
      (const __attribute__((address_space(1))) void*)g,
      (__attribute__((address_space(3))) void*)l, 16, 0, 0);
}

__global__ __launch_bounds__(512, 2) void kan_fused(
    const float* __restrict__ x,       // (16384,512)
    const uint4* __restrict__ B16,     // [512][576] packed fp16
    const float2* __restrict__ cst,    // (512,) per-dim (g0, 1/h)
    const float* __restrict__ rsc,     // (1,)
    float* __restrict__ out)           // (16384,512)
{
  __shared__ uint4 Bs[4][2048];        // [j][512 n-rows][4 chunks] = 128 KB
  __shared__ uint4 As[4][256];         // [j][64 rows][4 chunks]    =  16 KB

  const int tid  = threadIdx.x;        // 0..511
  const int lane = tid & 63;
  const int wv   = tid >> 6;           // 0..7

  // XCD-chunked bijective swizzle (256 = 8 * 32).
  const int bid  = blockIdx.x;
  const int wg   = ((bid & 7) << 5) | (bid >> 3);
  const int row0 = wg << 6;            // m-panel * 64

  const int q    = lane >> 4;          // k-chunk 0..3
  const int l15  = lane & 15;
  const int cq   = (q + ((l15 >> 1) & 3)) & 3;   // read-side un-rotation

  // gen mapping: thread = (grow, ggc, gpar) = (tid>>3, (tid>>1)&3, tid&1).
  // Per group g it evals tiles kt0 = 4g+2*gpar and kt0+1 for chunk ggc:
  //   spline (g<32): dims 128*ggc + 4g + 2*gpar (+1)  -> one float2 of x
  //   silu  (g>=32): dim-blocks j=4*(kt-128)+ggc       -> four float4 of x
  const int grow  = tid >> 3;          // 0..63
  const int ggc   = (tid >> 1) & 3;    // logical chunk
  const int gpar  = tid & 1;           // which pair of tiles in group
  const int aslot = grow * 4 + ((ggc + (grow >> 1)) & 3);  // rotated As slot
  const float* xrow = x + (size_t)(row0 + grow) * IN_DIM;

  // B staging: wave wv fills Bs[j] slots [wv*256, +256), 4 gloads per tile.
  const uint4* gsb[4];
  #pragma unroll
  for (int h = 0; h < 4; ++h) {
    int s = wv * 256 + h * 64 + lane;
    gsb[h] = B16 + (size_t)(s >> 2) * KCH + (s & 3);
  }

  f32x4 acc[4][4];
  #pragma unroll
  for (int a = 0; a < 4; ++a)
    #pragma unroll
    for (int b = 0; b < 4; ++b)
      acc[a][b] = (f32x4){0.f, 0.f, 0.f, 0.f};

  // ---- gen-input prefetch registers, loaded for group 0 ----
  float2 xv_c = {0.f, 0.f};
  float4 cs_c = {0.f, 0.f, 0.f, 0.f};
  float4 s0_c = cs_c, s1_c = cs_c, s2_c = cs_c, s3_c = cs_c;
  {
    const int d0 = 128 * ggc + 2 * gpar;               // group 0 dims
    xv_c = *(const float2*)(xrow + d0);
    cs_c = *(const float4*)(cst + d0);
  }

  // ==== 36 groups of 4 k-tiles: 32 spline + 4 silu ====
  for (int g = 0; g < 36; ++g) {
    // ---- stage 4 B-tiles (16 gloads per wave) ----
    #pragma unroll
    for (int j = 0; j < 4; ++j) {
      const int kt = 4 * g + j;
      #pragma unroll
      for (int h = 0; h < 4; ++h)
        gload_lds16(gsb[h] + kt * 4, &Bs[j][wv * 256 + h * 64]);
    }

    // ---- prefetch gen inputs for group g+1 (used next iteration) ----
    float2 xv_n = {0.f, 0.f};
    float4 cs_n = {0.f, 0.f, 0.f, 0.f};
    float4 s0_n = cs_n, s1_n = cs_n, s2_n = cs_n, s3_n = cs_n;
    const int gn = g + 1;
    if (gn < 32) {
      const int d0 = 128 * ggc + 4 * gn + 2 * gpar;
      xv_n = *(const float2*)(xrow + d0);
      cs_n = *(const float4*)(cst + d0);
    } else if (gn < 36) {
      const int kt0 = 4 * gn + 2 * gpar;               // 128..142
      const int ja  = 4 * (kt0 - 128) + ggc;
      s0_n = *(const float4*)(xrow + ja * 8);
      s1_n = *(const float4*)(xrow + ja * 8 + 4);
      s2_n = *(const float4*)(xrow + ja * 8 + 32);     // jb = ja+4
      s3_n = *(const float4*)(xrow + ja * 8 + 36);
    }

    // ---- gen 2 evals from CURRENT regs (no load-to-use chain) ----
    const int j0 = 2 * gpar;
    if (g < 32) {
      As[j0][aslot]     = basis8(xv_c.x, cs_c.x, cs_c.y);
      As[j0 + 1][aslot] = basis8(xv_c.y, cs_c.z, cs_c.w);
    } else {
      As[j0][aslot]     = pk8(silu4(s0_c), silu4(s1_c));
      As[j0 + 1][aslot] = pk8(silu4(s2_c), silu4(s3_c));
    }
    __syncthreads();                                   // drains vm + lgkm

    // ---- compute 4 tiles: 64 MFMA per wave ----
    #pragma unroll
    for (int j = 0; j < 4; ++j) {
      half8 af[4], bg[4];
      #pragma unroll
      for (int tm = 0; tm < 4; ++tm)
        af[tm] = *(const half8*)&As[j][(tm * 16 + l15) * 4 + cq];
      #pragma unroll
      for (int tn = 0; tn < 4; ++tn)
        bg[tn] = *(const half8*)&Bs[j][(wv * 64 + tn * 16 + l15) * 4 + cq];
      #pragma unroll
      for (int tm = 0; tm < 4; ++tm)
        #pragma unroll
        for (int tn = 0; tn < 4; ++tn)
          acc[tm][tn] = __builtin_amdgcn_mfma_f32_16x16x32_f16(
              af[tm], bg[tn], acc[tm][tn], 0, 0, 0);
    }
    __syncthreads();                                   // protect As/Bs reuse

    xv_c = xv_n; cs_c = cs_n;
    s0_c = s0_n; s1_c = s1_n; s2_c = s2_n; s3_c = s3_n;
  }

  // ===== epilogue: + res_scale*x, tanh, store. C/D row=(lane>>4)*4+reg ====
  const float rs = rsc[0];
  #pragma unroll
  for (int tm = 0; tm < 4; ++tm) {
    #pragma unroll
    for (int tn = 0; tn < 4; ++tn) {
      #pragma unroll
      for (int r = 0; r < 4; ++r) {
        int m = row0 + tm * 16 + q * 4 + r;
        int n = wv * 64 + tn * 16 + l15;
        float xg = x[(size_t)m * IN_DIM + n];
        float y  = acc[tm][tn][r] + rs * xg;
        float e  = __expf(-2.f * fabsf(y));
        float t  = copysignf((1.f - e) / (1.f + e), y);
        out[(size_t)m * OUT_DIM + n] = t;
      }
    }
  }
}

// ===========================================================================
// Fallback: verified R5 fused kernel (used only if workspace is too small).
// ===========================================================================
__device__ __forceinline__ int swz(int r, int c) {
  return r * 4 + ((c + (r >> 1)) & 3);
}

__global__ __launch_bounds__(256, 2) void kan_main(
    const float* __restrict__ x, const float* __restrict__ coeffs,
    const float* __restrict__ bwt, const float* __restrict__ gsl,
    const float* __restrict__ gstart, const float* __restrict__ rsc,
    float* __restrict__ out)
{
  __shared__ uint4 At[512];
  __shared__ uint4 Bt[512];
  __shared__ float2 Cs[512];

  const int tid  = threadIdx.x;
  const int lane = tid & 63;
  const int wv   = tid >> 6;
  const int row0 = blockIdx.y << 7;
  const int n0   = blockIdx.x << 7;

  const int q    = lane >> 4;
  const int l15  = lane & 15;
  const int wrow = (wv >> 1) << 6;
  const int wcol = (wv & 1) << 6;

  for (int d = tid; d < IN_DIM; d += 256) {
    float v  = gsl[d * 11];
    float sp = fmaxf(v, 0.f) + log1pf(expf(-fabsf(v)));
    Cs[d] = make_float2(gstart[d], 1.f / sp);
  }
  __syncthreads();

  f32x4 acc[4][4];
  #pragma unroll
  for (int a = 0; a < 4; ++a)
    #pragma unroll
    for (int b = 0; b < 4; ++b)
      acc[a][b] = (f32x4){0.f, 0.f, 0.f, 0.f};

  const int br0 = tid >> 2,        bc0 = tid & 3;
  const int br1 = (tid + 256) >> 2, bc1 = tid & 3;

  auto do_mfma = [&]() {
    half8 af[4], bg[4];
    #pragma unroll
    for (int tm = 0; tm < 4; ++tm) {
      int m = wrow + tm * 16 + l15;
      af[tm] = *(const half8*)&At[swz(m, q)];
    }
    #pragma unroll
    for (int tn = 0; tn < 4; ++tn) {
      int n = wcol + tn * 16 + l15;
      bg[tn] = *(const half8*)&Bt[swz(n, q)];
    }
    #pragma unroll
    for (int tm = 0; tm < 4; ++tm)
      #pragma unroll
      for (int tn = 0; tn < 4; ++tn)
        acc[tm][tn] = __builtin_amdgcn_mfma_f32_16x16x32_f16(
            af[tm], bg[tn], acc[tm][tn], 0, 0, 0);
  };

  const float* bp0 = coeffs + (size_t)(n0 + br0) * 4096 + 1024 * bc0;
  const float* bp1 = coeffs + (size_t)(n0 + br1) * 4096 + 1024 * bc1;
  const float* xp0 = x + (size_t)(row0 + lane) * IN_DIM + 128 * wv;
  const float* xp1 = xp0 + (size_t)64 * IN_DIM;

  for (int kt4 = 0; kt4 < 32; ++kt4) {
    float4 xa = *(const float4*)(xp0 + kt4 * 4);
    float4 xb = *(const float4*)(xp1 + kt4 * 4);
    float xr0[4] = {xa.x, xa.y, xa.z, xa.w};
    float xr1[4] = {xb.x, xb.y, xb.z, xb.w};
    #pragma unroll
    for (int j = 0; j < 4; ++j) {
      const int kt = kt4 * 4 + j;
      const float* s0 = bp0 + kt * 8;
      const float* s1 = bp1 + kt * 8;
      float4 b0a = *(const float4*)(s0), b0b = *(const float4*)(s0 + 4);
      float4 b1a = *(const float4*)(s1), b1b = *(const float4*)(s1 + 4);

      float2 c = Cs[128 * wv + kt];
      uint4 p0 = basis8(xr0[j], c.x, c.y);
      uint4 p1 = basis8(xr1[j], c.x, c.y);

      Bt[swz(br0, bc0)] = pk8(b0a, b0b);
      Bt[swz(br1, bc1)] = pk8(b1a, b1b);
      At[swz(lane, wv)]      = p0;
      At[swz(lane + 64, wv)] = p1;
      __syncthreads();
      do_mfma();
      __syncthreads();
    }
  }

  for (int kt = 0; kt < 16; ++kt) {
    const int k0 = kt * 32;
    const float* s0 = bwt + (size_t)(n0 + br0) * 512 + k0 + bc0 * 8;
    const float* s1 = bwt + (size_t)(n0 + br1) * 512 + k0 + bc1 * 8;
    float4 b0a = *(const float4*)(s0), b0b = *(const float4*)(s0 + 4);
    float4 b1a = *(const float4*)(s1), b1b = *(const float4*)(s1 + 4);

    uint4 p[2];
    #pragma unroll
    for (int rr = 0; rr < 2; ++rr) {
      int idx = tid + rr * 256;
      int r = idx >> 2, cch = idx & 3;
      const float* xs = x + (size_t)(row0 + r) * IN_DIM + k0 + cch * 8;
      float4 xc = *(const float4*)(xs), xd = *(const float4*)(xs + 4);
      float f[8] = {xc.x, xc.y, xc.z, xc.w, xd.x, xd.y, xd.z, xd.w};
      #pragma unroll
      for (int jj = 0; jj < 8; ++jj) f[jj] = f[jj] / (1.f + __expf(-f[jj]));
      p[rr].x = pk2(f[0], f[1]); p[rr].y = pk2(f[2], f[3]);
      p[rr].z = pk2(f[4], f[5]); p[rr].w = pk2(f[6], f[7]);
    }

    Bt[swz(br0, bc0)] = pk8(b0a, b0b);
    Bt[swz(br1, bc1)] = pk8(b1a, b1b);
    #pragma unroll
    for (int rr = 0; rr < 2; ++rr) {
      int idx = tid + rr * 256;
      At[swz(idx >> 2, idx & 3)] = p[rr];
    }
    __syncthreads();
    do_mfma();
    __syncthreads();
  }

  const float rs = rsc[0];
  #pragma unroll
  for (int tm = 0; tm < 4; ++tm) {
    #pragma unroll
    for (int tn = 0; tn < 4; ++tn) {
      #pragma unroll
      for (int r = 0; r < 4; ++r) {
        int m = row0 + wrow + tm * 16 + q * 4 + r;
        int n = n0 + wcol + tn * 16 + l15;
        float xv = x[(size_t)m * IN_DIM + n];
        float y  = acc[tm][tn][r] + rs * xv;
        float e  = __expf(-2.f * fabsf(y));
        float t  = copysignf((1.f - e) / (1.f + e), y);
        out[(size_t)m * OUT_DIM + n] = t;
      }
    }
  }
}

// ---------------------------------------------------------------------------
extern "C" void kernel_launch(void* const* d_in, const int* in_sizes, int n_in,
                              void* d_out, int out_size, void* d_ws, size_t ws_size,
                              hipStream_t stream) {
  const float* x      = (const float*)d_in[0];
  const float* coeffs = (const float*)d_in[1];
  const float* bwt    = (const float*)d_in[2];
  const float* gsl    = (const float*)d_in[3];
  const float* gstart = (const float*)d_in[4];
  const float* rsc    = (const float*)d_in[5];
  float* out = (float*)d_out;
  (void)in_sizes; (void)n_in; (void)out_size;

  const size_t needB = (size_t)OUT_DIM * KCH * 16;   // 4,718,592 B
  const size_t needC = (size_t)IN_DIM * 8;           //     4,096 B

  if (d_ws != nullptr && ws_size >= needB + needC) {
    uint4*  B16 = (uint4*)d_ws;
    float2* cst = (float2*)((char*)d_ws + needB);
    hipLaunchKernelGGL(kan_prep0, dim3(1154), dim3(256), 0, stream,
                       coeffs, bwt, gsl, gstart, B16, cst);
    hipLaunchKernelGGL(kan_fused, dim3(256), dim3(512), 0, stream,
                       x, (const uint4*)B16, (const float2*)cst, rsc, out);
  } else {
    hipLaunchKernelGGL(kan_main, dim3(4, 128), dim3(256), 0, stream,
                       x, coeffs, bwt, gsl, gstart, rsc, out);
  }
}

// Round 14
// 210.293 us; speedup vs baseline: 1.3121x; 1.2047x over previous
//
#include <hip/hip_runtime.h>
#include <stdint.h>
#include <stddef.h>

// ---------------------------------------------------------------------------
// BSplineKANLayer — R15: R12 geometry (2 blocks/CU) + R14 register prefetch.
// R14 post-mortem: gen-once @ 1 block/CU = 177us; stall ~106us because grid
// =256 -> exactly one block per CU -> every barrier stalls the whole CU (no
// co-resident block). R12 (grid=512, 2 blocks/CU) remains best fused at
// 141us despite 2x gen work. R15 = R12's exact structure (BM=64 x BN=256,
// G=4, 4 waves, 80KB LDS) + gen inputs prefetched ONE GROUP AHEAD into
// registers (single delta vs R12's measured 141):
//   per group: stage 16 gloads -> prefetch g+1 inputs -> gen 4 evals from
//   CURRENT regs -> bar -> 4x[ds_read + 16 MFMA] -> bar.
// Layouts/rotation identical to R10-R14 (all passed, absmax 0.0105).
// ---------------------------------------------------------------------------

typedef __attribute__((ext_vector_type(8))) _Float16 half8;  // 8 fp16 = 4 VGPRs
typedef __attribute__((ext_vector_type(4))) float f32x4;

#define IN_DIM   512
#define OUT_DIM  512
#define BATCH    16384
#define KCH      576     // uint4 chunks per row: 4608 fp16 = 576 * 16B

// RNE f32 -> fp16 pair packed in a uint (a low 16, b high 16)
__device__ __forceinline__ unsigned pk2(float a, float b) {
  _Float16 ha = (_Float16)a, hb = (_Float16)b;   // v_cvt_f16_f32 (RNE)
  unsigned short ua = __builtin_bit_cast(unsigned short, ha);
  unsigned short ub = __builtin_bit_cast(unsigned short, hb);
  return (unsigned)ua | ((unsigned)ub << 16);
}
__device__ __forceinline__ uint4 pk8(float4 a, float4 b) {
  uint4 r;
  r.x = pk2(a.x, a.y); r.y = pk2(a.z, a.w);
  r.z = pk2(b.x, b.y); r.w = pk2(b.z, b.w);
  return r;
}
__device__ __forceinline__ float4 silu4(float4 v) {
  float4 r;
  r.x = v.x / (1.f + __expf(-v.x));
  r.y = v.y / (1.f + __expf(-v.y));
  r.z = v.z / (1.f + __expf(-v.z));
  r.w = v.w / (1.f + __expf(-v.w));
  return r;
}

// branchless 64->32 funnel extract: bits [amt, amt+32) of p, 0 outside range
__device__ __forceinline__ uint32_t fsh(uint64_t p, int amt) {
  uint32_t lo = (uint32_t)(p >> (amt & 63));
  lo = (amt >= 0 && amt < 64) ? lo : 0u;
  uint32_t hi = (uint32_t)(p << ((-amt) & 63));
  hi = (amt < 0 && amt > -64) ? hi : 0u;
  return lo | hi;
}

// Windowed cubic basis (uniform grid; matches reference's single-step-denom
// recursion exactly — verified R5..R14): 8 fp16 values for one (row,dim).
__device__ __forceinline__ uint4 basis8(float xv, float g0, float rh) {
  float u  = (xv - g0) * rh;
  float tf = floorf(u);
  float f  = u - tf;
  int   t  = (int)tf;
  bool valid = (u >= 0.f) && (u < 11.f);
  t = min(max(t, 0), 10);
  float f2 = f * f, f3 = f2 * f;
  float omf = 1.f - f;
  float v0 = omf * omf * omf;                          // j = t-3
  float v1 = fmaf(f2, fmaf(3.f, f, -6.f), 4.f);        // j = t-2
  float v2 = fmaf(f, fmaf(f, fmaf(-3.f, f, 3.f), 3.f), 1.f);  // j = t-1
  float v3 = f3;                                       // j = t
  uint64_t pack = ((uint64_t)pk2(v2, v3) << 32) | (uint64_t)pk2(v0, v1);
  pack = valid ? pack : 0ull;
  const int base = 48 - 16 * t;                        // in [-112, 48]
  uint4 r;
  r.x = fsh(pack, base);
  r.y = fsh(pack, base + 32);
  r.z = fsh(pack, base + 64);
  r.w = fsh(pack, base + 96);
  return r;
}

// ===========================================================================
// Kernel 1: merged prep — blocks 0..1151 pack B16 (4.7 MB), blocks 1152..1153
// compute per-dim consts (g0, 1/softplus). One launch.
// B16 stored slot s = kt*4 + sc of row n holds logical chunk c = (sc-rot)&3,
// rot = (n>>1)&3:  kt<128: dim = 128c+kt -> coeffs; kt>=128: j=4(kt-128)+c
// -> bwt.
// ===========================================================================
__global__ __launch_bounds__(256) void kan_prep0(
    const float* __restrict__ coeffs,  // (512,4096)
    const float* __restrict__ bwt,     // (512,512)
    const float* __restrict__ gsl,     // (512,11)
    const float* __restrict__ gstart,  // (512,1)
    uint4* __restrict__ B16,           // [512][576]
    float2* __restrict__ cst)          // (512,)
{
  const int bid = blockIdx.x;
  if (bid < 1152) {
    int id = bid * 256 + threadIdx.x;                  // < 512*576
    int n  = id / KCH;
    int s  = id - n * KCH;
    int kt = s >> 2, sc = s & 3;
    int rot = (n >> 1) & 3;
    int c   = (sc - rot) & 3;
    const float* src;
    if (kt < 128) {
      int dim = 128 * c + kt;
      src = coeffs + (size_t)n * 4096 + dim * 8;
    } else {
      int j = 4 * (kt - 128) + c;
      src = bwt + (size_t)n * 512 + j * 8;
    }
    float4 a = *(const float4*)src, b = *(const float4*)(src + 4);
    B16[id] = pk8(a, b);
  } else {
    int d = (bid - 1152) * 256 + threadIdx.x;
    if (d < IN_DIM) {
      float v  = gsl[d * 11];                          // all 11 identical
      float sp = fmaxf(v, 0.f) + log1pf(expf(-fabsf(v)));  // softplus = h
      cst[d] = make_float2(gstart[d], 1.f / sp);
    }
  }
}

// ===========================================================================
// Kernel 2: fused basis-gen + GEMM + epilogue. BM=64 x BN=256, G=4.
// grid = 512 (XCD-chunked), 256 thr (4 waves). LDS 80KB -> 2 blocks/CU.
// ===========================================================================
__device__ __forceinline__ void gload_lds16(const uint4* g, uint4* l) {
  __builtin_amdgcn_global_load_lds(
      (const __attribute__((address_space(1))) void*)g,
      (__attribute__((address_space(3))) void*)l, 16, 0, 0);
}

__global__ __launch_bounds__(256, 2) void kan_fused(
    const float* __restrict__ x,       // (16384,512)
    const uint4* __restrict__ B16,     // [512][576] packed fp16
    const float2* __restrict__ cst,    // (512,) per-dim (g0, 1/h)
    const float* __restrict__ rsc,     // (1,)
    float* __restrict__ out)           // (16384,512)
{
  __shared__ uint4 Bs[4][1024];        // [j][256 n-rows][4 chunks] = 64 KB
  __shared__ uint4 As[4][256];         // [j][64 rows][4 chunks]    = 16 KB

  const int tid  = threadIdx.x;
  const int lane = tid & 63;
  const int wv   = tid >> 6;

  // XCD-chunked bijective swizzle (512 % 8 == 0).
  const int bid  = blockIdx.x;
  const int wg   = ((bid & 7) << 6) | (bid >> 3);
  const int row0 = (wg >> 1) << 6;     // m-panel * 64
  const int n0   = (wg & 1) << 8;      // n-half * 256

  const int q    = lane >> 4;          // k-chunk 0..3
  const int l15  = lane & 15;
  const int cq   = (q + ((l15 >> 1) & 3)) & 3;   // read-side un-rotation

  // A-gen mapping: thread (grow, gc) = (tid>>2, tid&3), 4 evals per group
  const int grow  = tid >> 2;          // 0..63 local row
  const int gc    = tid & 3;           // logical chunk
  const int aslot = grow * 4 + ((gc + (grow >> 1)) & 3);  // rotated As slot
  const float* xrow = x + (size_t)(row0 + grow) * IN_DIM;

  // B staging: wave wv fills Bs slots [wv*64 + h*256, +64), h=0..3
  const uint4* gsb[4];
  #pragma unroll
  for (int h = 0; h < 4; ++h) {
    int s = wv * 64 + h * 256 + lane;
    gsb[h] = B16 + (size_t)(n0 + (s >> 2)) * KCH + (s & 3);
  }

  f32x4 acc[4][4];
  #pragma unroll
  for (int a = 0; a < 4; ++a)
    #pragma unroll
    for (int b = 0; b < 4; ++b)
      acc[a][b] = (f32x4){0.f, 0.f, 0.f, 0.f};

  // ---- gen-input prefetch registers, loaded for group 0 (spline) ----
  float4 xv_c, c01_c, c23_c;
  float4 sl_c[8], sl_n[8];
  {
    const int d0 = 128 * gc;                           // group 0 dims
    xv_c  = *(const float4*)(xrow + d0);
    c01_c = *(const float4*)(cst + d0);
    c23_c = *(const float4*)(cst + d0 + 2);
  }
  #pragma unroll
  for (int i = 0; i < 8; ++i) sl_c[i] = (float4){0.f, 0.f, 0.f, 0.f};

  // ==== 36 groups of 4 k-tiles: 32 spline + 4 silu ====
  for (int g = 0; g < 36; ++g) {
    // ---- stage 4 B-tiles (16 gloads) ----
    #pragma unroll
    for (int j = 0; j < 4; ++j) {
      const int kt = g * 4 + j;
      #pragma unroll
      for (int h = 0; h < 4; ++h)
        gload_lds16(gsb[h] + kt * 4, &Bs[j][wv * 64 + h * 256]);
    }

    // ---- prefetch gen inputs for group g+1 ----
    float4 xv_n = {0.f, 0.f, 0.f, 0.f};
    float4 c01_n = xv_n, c23_n = xv_n;
    #pragma unroll
    for (int i = 0; i < 8; ++i) sl_n[i] = (float4){0.f, 0.f, 0.f, 0.f};
    const int gn = g + 1;
    if (gn < 32) {
      const int d0 = 128 * gc + gn * 4;
      xv_n  = *(const float4*)(xrow + d0);
      c01_n = *(const float4*)(cst + d0);
      c23_n = *(const float4*)(cst + d0 + 2);
    } else if (gn < 36) {
      #pragma unroll
      for (int j = 0; j < 4; ++j) {
        const int kp = (gn - 32) * 4 + j;              // 0..15
        const float* xs = xrow + (4 * kp + gc) * 8;
        sl_n[2 * j]     = *(const float4*)(xs);
        sl_n[2 * j + 1] = *(const float4*)(xs + 4);
      }
    }

    // ---- gen 4 A-tiles from CURRENT regs (no load-to-use chain) ----
    if (g < 32) {
      As[0][aslot] = basis8(xv_c.x, c01_c.x, c01_c.y);
      As[1][aslot] = basis8(xv_c.y, c01_c.z, c01_c.w);
      As[2][aslot] = basis8(xv_c.z, c23_c.x, c23_c.y);
      As[3][aslot] = basis8(xv_c.w, c23_c.z, c23_c.w);
    } else {
      #pragma unroll
      for (int j = 0; j < 4; ++j)
        As[j][aslot] = pk8(silu4(sl_c[2 * j]), silu4(sl_c[2 * j + 1]));
    }
    __syncthreads();                                   // drains vm + lgkm

    // ---- compute 4 tiles: 64 MFMA ----
    #pragma unroll
    for (int j = 0; j < 4; ++j) {
      half8 af[4], bg[4];
      #pragma unroll
      for (int tm = 0; tm < 4; ++tm)
        af[tm] = *(const half8*)&As[j][(tm * 16 + l15) * 4 + cq];
      #pragma unroll
      for (int tn = 0; tn < 4; ++tn)
        bg[tn] = *(const half8*)&Bs[j][(wv * 64 + tn * 16 + l15) * 4 + cq];
      #pragma unroll
      for (int tm = 0; tm < 4; ++tm)
        #pragma unroll
        for (int tn = 0; tn < 4; ++tn)
          acc[tm][tn] = __builtin_amdgcn_mfma_f32_16x16x32_f16(
              af[tm], bg[tn], acc[tm][tn], 0, 0, 0);
    }
    __syncthreads();                                   // protect As/Bs reuse

    xv_c = xv_n; c01_c = c01_n; c23_c = c23_n;
    #pragma unroll
    for (int i = 0; i < 8; ++i) sl_c[i] = sl_n[i];
  }

  // ===== epilogue: + res_scale*x, tanh, store. C/D row=(lane>>4)*4+reg ====
  const float rs = rsc[0];
  #pragma unroll
  for (int tm = 0; tm < 4; ++tm) {
    #pragma unroll
    for (int tn = 0; tn < 4; ++tn) {
      #pragma unroll
      for (int r = 0; r < 4; ++r) {
        int m = row0 + tm * 16 + q * 4 + r;
        int n = n0 + wv * 64 + tn * 16 + l15;
        float xg = x[(size_t)m * IN_DIM + n];
        float y  = acc[tm][tn][r] + rs * xg;
        float e  = __expf(-2.f * fabsf(y));
        float t  = copysignf((1.f - e) / (1.f + e), y);
        out[(size_t)m * OUT_DIM + n] = t;
      }
    }
  }
}

// ===========================================================================
// Fallback: verified R5 fused kernel (used only if workspace is too small).
// ===========================================================================
__device__ __forceinline__ int swz(int r, int c) {
  return r * 4 + ((c + (r >> 1)) & 3);
}

__global__ __launch_bounds__(256, 2) void kan_main(
    const float* __restrict__ x, const float* __restrict__ coeffs,
    const float* __restrict__ bwt, const float* __restrict__ gsl,
    const float* __restrict__ gstart, const float* __restrict__ rsc,
    float* __restrict__ out)
{
  __shared__ uint4 At[512];
  __shared__ uint4 Bt[512];
  __shared__ float2 Cs[512];

  const int tid  = threadIdx.x;
  const int lane = tid & 63;
  const int wv   = tid >> 6;
  const int row0 = blockIdx.y << 7;
  const int n0   = blockIdx.x << 7;

  const int q    = lane >> 4;
  const int l15  = lane & 15;
  const int wrow = (wv >> 1) << 6;
  const int wcol = (wv & 1) << 6;

  for (int d = tid; d < IN_DIM; d += 256) {
    float v  = gsl[d * 11];
    float sp = fmaxf(v, 0.f) + log1pf(expf(-fabsf(v)));
    Cs[d] = make_float2(gstart[d], 1.f / sp);
  }
  __syncthreads();

  f32x4 acc[4][4];
  #pragma unroll
  for (int a = 0; a < 4; ++a)
    #pragma unroll
    for (int b = 0; b < 4; ++b)
      acc[a][b] = (f32x4){0.f, 0.f, 0.f, 0.f};

  const int br0 = tid >> 2,        bc0 = tid & 3;
  const int br1 = (tid + 256) >> 2, bc1 = tid & 3;

  auto do_mfma = [&]() {
    half8 af[4], bg[4];
    #pragma unroll
    for (int tm = 0; tm < 4; ++tm) {
      int m = wrow + tm * 16 + l15;
      af[tm] = *(const half8*)&At[swz(m, q)];
    }
    #pragma unroll
    for (int tn = 0; tn < 4; ++tn) {
      int n = wcol + tn * 16 + l15;
      bg[tn] = *(const half8*)&Bt[swz(n, q)];
    }
    #pragma unroll
    for (int tm = 0; tm < 4; ++tm)
      #pragma unroll
      for (int tn = 0; tn < 4; ++tn)
        acc[tm][tn] = __builtin_amdgcn_mfma_f32_16x16x32_f16(
            af[tm], bg[tn], acc[tm][tn], 0, 0, 0);
  };

  const float* bp0 = coeffs + (size_t)(n0 + br0) * 4096 + 1024 * bc0;
  const float* bp1 = coeffs + (size_t)(n0 + br1) * 4096 + 1024 * bc1;
  const float* xp0 = x + (size_t)(row0 + lane) * IN_DIM + 128 * wv;
  const float* xp1 = xp0 + (size_t)64 * IN_DIM;

  for (int kt4 = 0; kt4 < 32; ++kt4) {
    float4 xa = *(const float4*)(xp0 + kt4 * 4);
    float4 xb = *(const float4*)(xp1 + kt4 * 4);
    float xr0[4] = {xa.x, xa.y, xa.z, xa.w};
    float xr1[4] = {xb.x, xb.y, xb.z, xb.w};
    #pragma unroll
    for (int j = 0; j < 4; ++j) {
      const int kt = kt4 * 4 + j;
      const float* s0 = bp0 + kt * 8;
      const float* s1 = bp1 + kt * 8;
      float4 b0a = *(const float4*)(s0), b0b = *(const float4*)(s0 + 4);
      float4 b1a = *(const float4*)(s1), b1b = *(const float4*)(s1 + 4);

      float2 c = Cs[128 * wv + kt];
      uint4 p0 = basis8(xr0[j], c.x, c.y);
      uint4 p1 = basis8(xr1[j], c.x, c.y);

      Bt[swz(br0, bc0)] = pk8(b0a, b0b);
      Bt[swz(br1, bc1)] = pk8(b1a, b1b);
      At[swz(lane, wv)]      = p0;
      At[swz(lane + 64, wv)] = p1;
      __syncthreads();
      do_mfma();
      __syncthreads();
    }
  }

  for (int kt = 0; kt < 16; ++kt) {
    const int k0 = kt * 32;
    const float* s0 = bwt + (size_t)(n0 + br0) * 512 + k0 + bc0 * 8;
    const float* s1 = bwt + (size_t)(n0 + br1) * 512 + k0 + bc1 * 8;
    float4 b0a = *(const float4*)(s0), b0b = *(const float4*)(s0 + 4);
    float4 b1a = *(const float4*)(s1), b1b = *(const float4*)(s1 + 4);

    uint4 p[2];
    #pragma unroll
    for (int rr = 0; rr < 2; ++rr) {
      int idx = tid + rr * 256;
      int r = idx >> 2, cch = idx & 3;
      const float* xs = x + (size_t)(row0 + r) * IN_DIM + k0 + cch * 8;
      float4 xc = *(const float4*)(xs), xd = *(const float4*)(xs + 4);
      float f[8] = {xc.x, xc.y, xc.z, xc.w, xd.x, xd.y, xd.z, xd.w};
      #pragma unroll
      for (int jj = 0; jj < 8; ++jj) f[jj] = f[jj] / (1.f + __expf(-f[jj]));
      p[rr].x = pk2(f[0], f[1]); p[rr].y = pk2(f[2], f[3]);
      p[rr].z = pk2(f[4], f[5]); p[rr].w = pk2(f[6], f[7]);
    }

    Bt[swz(br0, bc0)] = pk8(b0a, b0b);
    Bt[swz(br1, bc1)] = pk8(b1a, b1b);
    #pragma unroll
    for (int rr = 0; rr < 2; ++rr) {
      int idx = tid + rr * 256;
      At[swz(idx >> 2, idx & 3)] = p[rr];
    }
    __syncthreads();
    do_mfma();
    __syncthreads();
  }

  const float rs = rsc[0];
  #pragma unroll
  for (int tm = 0; tm < 4; ++tm) {
    #pragma unroll
    for (int tn = 0; tn < 4; ++tn) {
      #pragma unroll
      for (int r = 0; r < 4; ++r) {
        int m = row0 + wrow + tm * 16 + q * 4 + r;
        int n = n0 + wcol + tn * 16 + l15;
        float xv = x[(size_t)m * IN_DIM + n];
        float y  = acc[tm][tn][r] + rs * xv;
        float e  = __expf(-2.f * fabsf(y));
        float t  = copysignf((1.f - e) / (1.f + e), y);
        out[(size_t)m * OUT_DIM + n] = t;
      }
    }
  }
}

// ---------------------------------------------------------------------------
extern "C" void kernel_launch(void* const* d_in, const int* in_sizes, int n_in,
                              void* d_out, int out_size, void* d_ws, size_t ws_size,
                              hipStream_t stream) {
  const float* x      = (const float*)d_in[0];
  const float* coeffs = (const float*)d_in[1];
  const float* bwt    = (const float*)d_in[2];
  const float* gsl    = (const float*)d_in[3];
  const float* gstart = (const float*)d_in[4];
  const float* rsc    = (const float*)d_in[5];
  float* out = (float*)d_out;
  (void)in_sizes; (void)n_in; (void)out_size;

  const size_t needB = (size_t)OUT_DIM * KCH * 16;   // 4,718,592 B
  const size_t needC = (size_t)IN_DIM * 8;           //     4,096 B

  if (d_ws != nullptr && ws_size >= needB + needC) {
    uint4*  B16 = (uint4*)d_ws;
    float2* cst = (float2*)((char*)d_ws + needB);
    hipLaunchKernelGGL(kan_prep0, dim3(1154), dim3(256), 0, stream,
                       coeffs, bwt, gsl, gstart, B16, cst);
    hipLaunchKernelGGL(kan_fused, dim3(512), dim3(256), 0, stream,
                       x, (const uint4*)B16, (const float2*)cst, rsc, out);
  } else {
    hipLaunchKernelGGL(kan_main, dim3(4, 128), dim3(256), 0, stream,
                       x, coeffs, bwt, gsl, gstart, rsc, out);
  }
}